// Round 8
// baseline (185.920 us; speedup 1.0000x reference)
//
#include <hip/hip_runtime.h>
#include <math.h>

// Problem constants (from reference setup_inputs)
#define L0      3072
#define BATCH   1024
#define NNEG    512

// -------- workspace layout --------
// X0 : bf16[393216]            (feat @ w_self_0, bf16)
// Y0 : bf16[393216]            = X0 + 393216 elems
// H  : float @ 393216 (3072*512)   [A,B | C,D] layer-1 inputs
// R  : float @ 1966080 (3072*256)  layer-1 output, normalized
// aff: float @ 2752512 (1024)
// spPos @ 2753536, spNeg @ 2753537, rank @ 2753538 (1024 ints)

__device__ __forceinline__ float bf2f(unsigned short u) {
  return __uint_as_float(((unsigned)u) << 16);
}
__device__ __forceinline__ void store_out(float v, float* p) { *p = v; }
__device__ __forceinline__ void store_out(float v, unsigned short* p) {
  unsigned x = __float_as_uint(v);                 // f32 -> bf16 RNE
  *p = (unsigned short)((x + 0x7fff + ((x >> 16) & 1)) >> 16);
}

// Half-split matmul, 6 rows x 256 cols per 512-thread block (grid 512,
// 2 blocks/CU = 16 waves/CU). Wave w: half=w>>2, colg=(w>>1)&1, rowg=w&1.
// A-tile in LDS (broadcast ds_read_b128); W coalesced from global;
// unroll-4 lets the compiler software-pipeline with fine-grained waitcnts.
// NORM: fused row L2-normalization (mm2 only).
template<int K, int AW, int HOFF, bool NORM, typename OutT>
__global__ __launch_bounds__(512) void k_mm(
    const float* __restrict__ Ain,
    const float* __restrict__ W0, const float* __restrict__ W1,
    OutT* __restrict__ Out, const int ldo, const int outHalfOff,
    float* __restrict__ zbuf, const int zcount) {
  __shared__ float AT[6 * AW];
  __shared__ float rs[8][3];
  const int t = threadIdx.x;
  if (zbuf != nullptr && blockIdx.x == 0)
    for (int z = t; z < zcount; z += 512) zbuf[z] = 0.f;
  const int base = blockIdx.x * 6;
  {
    const float4* __restrict__ src = (const float4*)(Ain + base * AW);
    float4* __restrict__ dst = (float4*)AT;
    for (int idx = t; idx < 6 * AW / 4; idx += 512) dst[idx] = src[idx];
  }
  __syncthreads();

  const int wave = t >> 6;
  const int half = wave >> 2;
  const int colg = (wave >> 1) & 1;
  const int rowg = wave & 1;
  const int rg = rowg * 3;
  const int col = colg * 64 + (t & 63);
  const float* __restrict__ W = (half ? W1 : W0) + col;
  const float* __restrict__ A0 = AT + rg * AW + half * HOFF;

  float acc[3] = {0.f, 0.f, 0.f};
#pragma unroll 4
  for (int d = 0; d < K; d += 4) {
    float4 a[3];
#pragma unroll
    for (int r = 0; r < 3; ++r) a[r] = *(const float4*)&A0[r * AW + d];
    float w[4];
#pragma unroll
    for (int i2 = 0; i2 < 4; ++i2) w[i2] = W[(d + i2) * 128];
#pragma unroll
    for (int i2 = 0; i2 < 4; ++i2)
#pragma unroll
      for (int r = 0; r < 3; ++r)
        acc[r] = fmaf(((const float*)&a[r])[i2], w[i2], acc[r]);
  }

  float scale[3] = {1.f, 1.f, 1.f};
  if (NORM) {
    float p[3];
#pragma unroll
    for (int r = 0; r < 3; ++r) p[r] = acc[r] * acc[r];
#pragma unroll
    for (int off = 32; off > 0; off >>= 1)
#pragma unroll
      for (int r = 0; r < 3; ++r) p[r] += __shfl_xor(p[r], off, 64);
    if ((t & 63) == 0) { rs[wave][0] = p[0]; rs[wave][1] = p[1]; rs[wave][2] = p[2]; }
    __syncthreads();
#pragma unroll
    for (int r = 0; r < 3; ++r) {
      const float s = rs[rowg][r] + rs[rowg + 2][r] + rs[rowg + 4][r] + rs[rowg + 6][r];
      scale[r] = rsqrtf(fmaxf(s, 1e-12f));
    }
  }
  OutT* __restrict__ O = Out + half * outHalfOff;
#pragma unroll
  for (int r = 0; r < 3; ++r)
    store_out(acc[r] * scale[r], &O[(base + rg + r) * ldo + col]);
}

// Fused layer-0 + layer-1 aggregation, bf16 gathers, ONE barrier.
// 640 threads = 10 waves; wave j owns hop-row j. Lane lam: c8=lam&15 (8-col
// slot), sub=lam>>4 (stride-4 partition of the 25 nb2 rows). Indices: each
// lane<25 loads one nb2 index (single coalesced load), distributed in-loop
// via __shfl. Sub-partials combined via shfl_xor.
// H[i] = [A,B | C,D]:
//   A[c] = relu(X0[nb0[i]][c])
//   B[c] = relu(0.1 * sum10_j Y0[nb1[10i+j]][c])
//   C[c] = 0.1 * sum10_j relu(X0[nb1[10i+j]][c])
//   D[c] = 0.1 * sum10_j relu(0.04 * sum25_k Y0[nb2[(10i+j)*25+k]][c])
__global__ __launch_bounds__(640) void k_aggregate(
    const unsigned short* __restrict__ X0, const unsigned short* __restrict__ Y0,
    const int* __restrict__ nb0, const int* __restrict__ nb1,
    const int* __restrict__ nb2, float* __restrict__ H) {
  __shared__ float gB[10][128], gC[10][128], gD[10][128];
  const int i = blockIdx.x;
  const int t = threadIdx.x;
  const int n0 = nb0[i];                    // uniform s_load, in flight early
  const int j = t >> 6;                     // wave index = hop row j
  const int lam = t & 63;
  const int r = i * 10 + j;                 // wave-uniform
  int myidx = 0;
  if (lam < 25) myidx = nb2[r * 25 + lam];  // one coalesced 100B load/wave
  else if (lam == 25) myidx = nb1[r];
  const int c8 = lam & 15;
  const int sub = lam >> 4;

  float d8[8];
#pragma unroll
  for (int e = 0; e < 8; ++e) d8[e] = 0.f;
#pragma unroll
  for (int m = 0; m < 7; ++m) {
    const int k = sub + 4 * m;
    const int ridx = __shfl(myidx, k, 64);  // ds_bpermute distribute
    if (k < 25) {
      const float4 raw = *(const float4*)(Y0 + ridx * 128 + c8 * 8);  // 8 bf16
      const unsigned short* u = (const unsigned short*)&raw;
#pragma unroll
      for (int e = 0; e < 8; ++e) d8[e] += bf2f(u[e]);
    }
  }
#pragma unroll
  for (int e = 0; e < 8; ++e) d8[e] += __shfl_xor(d8[e], 16, 64);
#pragma unroll
  for (int e = 0; e < 8; ++e) d8[e] += __shfl_xor(d8[e], 32, 64);

  const int r1 = __shfl(myidx, 25, 64);
  if (sub == 0) {
#pragma unroll
    for (int e = 0; e < 8; ++e) gD[j][c8 * 8 + e] = fmaxf(d8[e] * 0.04f, 0.f);
    const float4 raw = *(const float4*)(Y0 + r1 * 128 + c8 * 8);
    const unsigned short* u = (const unsigned short*)&raw;
#pragma unroll
    for (int e = 0; e < 8; ++e) gB[j][c8 * 8 + e] = bf2f(u[e]);
  } else if (sub == 1) {
    const float4 raw = *(const float4*)(X0 + r1 * 128 + c8 * 8);
    const unsigned short* u = (const unsigned short*)&raw;
#pragma unroll
    for (int e = 0; e < 8; ++e) gC[j][c8 * 8 + e] = fmaxf(bf2f(u[e]), 0.f);
  }
  __syncthreads();

  if (t < 512) {
    const int q = t >> 7, c = t & 127;
    float v;
    if (q == 0) {
      v = fmaxf(bf2f(X0[n0 * 128 + c]), 0.f);
    } else {
      const float* g = (q == 1) ? &gB[0][0] : (q == 2) ? &gC[0][0] : &gD[0][0];
      float s = 0.f;
#pragma unroll
      for (int jj = 0; jj < 10; ++jj) s += g[jj * 128 + c];
      v = s * 0.1f;
      if (q == 1) v = fmaxf(v, 0.f);
    }
    H[i * 512 + t] = v;
  }
}

__device__ __forceinline__ float softplusf(float x) {
  return fmaxf(x, 0.f) + log1pf(expf(-fabsf(x)));
}

// One block per b: 64 lanes stage src/pos rows to LDS with coalesced float4
// loads (and write src_emb to d_out); lane 0 runs the EXACT sequential fmaf
// chain d=0..255 (identical values + op order to k_neg's accumulators ->
// exact-tie reproduction for the reference's stable double-argsort).
// Extracted from k_neg: in-block recompute serialized every k_neg block
// behind an uncoalesced latency chain (R7 post-mortem).
__global__ __launch_bounds__(64) void k_aff(
    const float* __restrict__ O, const int* __restrict__ src_idx,
    const int* __restrict__ pos_idx, float* __restrict__ out_src,
    float* __restrict__ aff, float* __restrict__ spPos) {
  __shared__ float4 sv[64], pv[64];
  const int b = blockIdx.x;
  const int q = threadIdx.x;
  const float4 vs = ((const float4*)O)[src_idx[b] * 64 + q];
  ((float4*)out_src)[b * 64 + q] = vs;
  sv[q] = vs;
  pv[q] = ((const float4*)O)[pos_idx[b] * 64 + q];
  __syncthreads();
  if (q == 0) {
    float a = 0.f;
#pragma unroll 8
    for (int dd = 0; dd < 64; ++dd) {
      const float4 s4 = sv[dd];
      const float4 p4 = pv[dd];
      a = fmaf(s4.x, p4.x, a);
      a = fmaf(s4.y, p4.y, a);
      a = fmaf(s4.z, p4.z, a);
      a = fmaf(s4.w, p4.w, a);
    }
    aff[b] = a;
    atomicAdd(spPos, softplusf(-a));
  }
}

// neg_aff 32x32 tile per 256-thread block; grid 512 = 2 blocks/CU.
// Thread = 2x2 register tile; per 4-dd chunk: 4 ds_read_b128 + 16 fma.
// LDS stride 260: staging float4-aligned, N-reads 2-way (free), S-reads
// broadcast. aff read from global (computed by k_aff with the identical
// chain). rank += count(neg_aff >= aff) — ties count, positive sorts last.
__global__ __launch_bounds__(256) void k_neg(
    const float* __restrict__ O, const int* __restrict__ src_idx,
    const int* __restrict__ neg_idx, const float* __restrict__ aff,
    int* __restrict__ rank, float* __restrict__ spNeg) {
  __shared__ float S[32][260];
  __shared__ float N[32][260];
  __shared__ float affL[32];
  const int t = threadIdx.x;
  const int rowBase = (blockIdx.x >> 4) * 32;
  const int colBase = (blockIdx.x & 15) * 32;
  if (t < 32) affL[t] = aff[rowBase + t];

  // stage 32 src rows + 32 neg rows (float4 granularity)
  for (int idx = t; idx < 64 * 64; idx += 256) {
    const int row = idx >> 6, q = idx & 63;
    if (row < 32) {
      *(float4*)&S[row][q * 4] =
          ((const float4*)O)[src_idx[rowBase + row] * 64 + q];
    } else {
      *(float4*)&N[row - 32][q * 4] =
          ((const float4*)O)[neg_idx[colBase + row - 32] * 64 + q];
    }
  }
  __syncthreads();

  const int r2 = t >> 4, c2 = t & 15;
  float a00 = 0.f, a01 = 0.f, a10 = 0.f, a11 = 0.f;
  for (int dd = 0; dd < 256; dd += 4) {
    const float4 s0 = *(const float4*)&S[r2][dd];
    const float4 s1 = *(const float4*)&S[r2 + 16][dd];
    const float4 n0 = *(const float4*)&N[c2][dd];
    const float4 n1 = *(const float4*)&N[c2 + 16][dd];
#pragma unroll
    for (int e = 0; e < 4; ++e) {
      const float se0 = ((const float*)&s0)[e], se1 = ((const float*)&s1)[e];
      const float ne0 = ((const float*)&n0)[e], ne1 = ((const float*)&n1)[e];
      a00 = fmaf(se0, ne0, a00);
      a01 = fmaf(se0, ne1, a01);
      a10 = fmaf(se1, ne0, a10);
      a11 = fmaf(se1, ne1, a11);
    }
  }

  float sp = softplusf(a00) + softplusf(a01) + softplusf(a10) + softplusf(a11);
#pragma unroll
  for (int off = 32; off > 0; off >>= 1) sp += __shfl_down(sp, off, 64);
  if ((t & 63) == 0) atomicAdd(spNeg, sp);

  const float af0 = affL[r2], af1 = affL[r2 + 16];
  int c0 = (a00 >= af0 ? 1 : 0) + (a01 >= af0 ? 1 : 0);
  int c1 = (a10 >= af1 ? 1 : 0) + (a11 >= af1 ? 1 : 0);
#pragma unroll
  for (int off = 8; off > 0; off >>= 1) {
    c0 += __shfl_down(c0, off, 16);
    c1 += __shfl_down(c1, off, 16);
  }
  if (c2 == 0) {
    if (c0) atomicAdd(&rank[rowBase + r2], c0);
    if (c1) atomicAdd(&rank[rowBase + r2 + 16], c1);
  }
}

// mrr + loss scalars.
__global__ __launch_bounds__(256) void k_finalize(
    const int* __restrict__ rank, const float* __restrict__ spPos,
    const float* __restrict__ spNeg, float* __restrict__ out) {
  const int t = threadIdx.x;
  float s = 0.f;
  for (int i = t; i < BATCH; i += 256) s += 1.f / (float)(rank[i] + 1);
#pragma unroll
  for (int off = 32; off > 0; off >>= 1) s += __shfl_down(s, off, 64);
  __shared__ float wsum[4];
  if ((t & 63) == 0) wsum[t >> 6] = s;
  __syncthreads();
  if (t == 0) {
    float mrr = (wsum[0] + wsum[1] + wsum[2] + wsum[3]) * (1.f / 1024.f);
    float loss = (spPos[0] + spNeg[0]) * (1.f / 1024.f);
    out[BATCH * 256]     = loss;
    out[BATCH * 256 + 1] = mrr;
  }
}

extern "C" void kernel_launch(void* const* d_in, const int* in_sizes, int n_in,
                              void* d_out, int out_size, void* d_ws, size_t ws_size,
                              hipStream_t stream) {
  const float* feat   = (const float*)d_in[1];
  const int* src_idx  = (const int*)d_in[2];
  const int* pos_idx  = (const int*)d_in[3];
  const int* neg_idx  = (const int*)d_in[4];
  const int* nb0      = (const int*)d_in[5];
  const int* nb1      = (const int*)d_in[6];
  const int* nb2      = (const int*)d_in[7];
  const float* ws0    = (const float*)d_in[8];
  const float* wn0    = (const float*)d_in[9];
  const float* ws1    = (const float*)d_in[10];
  const float* wn1    = (const float*)d_in[11];

  float* wsf = (float*)d_ws;
  unsigned short* X0 = (unsigned short*)d_ws;       // bf16[393216]
  unsigned short* Y0 = X0 + 393216;                 // bf16[393216]
  float* H     = wsf + 393216;                      // 3072*512
  float* R     = wsf + 1966080;                     // 3072*256
  float* aff   = wsf + 2752512;
  float* spPos = wsf + 2753536;
  float* spNeg = wsf + 2753537;
  int*   rank  = (int*)(wsf + 2753538);
  float* out   = (float*)d_out;

  // X0 = bf16(feat@ws0), Y0 = bf16(feat@wn0); block 0 zeroes spPos/spNeg/rank
  k_mm<128, 128, 0, false, unsigned short><<<L0 / 6, 512, 0, stream>>>(
      feat, ws0, wn0, X0, 128, 393216, spPos, 1026);
  k_aggregate<<<L0, 640, 0, stream>>>(X0, Y0, nb0, nb1, nb2, H);
  // R[:, :128] = H[:, :256]@ws1 ; R[:, 128:] = H[:, 256:]@wn1 ; + L2-norm
  k_mm<256, 512, 256, true, float><<<L0 / 6, 512, 0, stream>>>(
      H, ws1, wn1, R, 256, 128, nullptr, 0);
  k_aff<<<BATCH, 64, 0, stream>>>(R, src_idx, pos_idx, out, aff, spPos);
  k_neg<<<512, 256, 0, stream>>>(R, src_idx, neg_idx, aff, rank, spNeg);
  k_finalize<<<1, 256, 0, stream>>>(rank, spPos, spNeg, out);
}

// Round 9
// 166.164 us; speedup vs baseline: 1.1189x; 1.1189x over previous
//
#include <hip/hip_runtime.h>
#include <math.h>

// Problem constants (from reference setup_inputs)
#define L0      3072
#define BATCH   1024
#define NNEG    512
#define LDP     264   // padded bf16 row stride in LDS (breaks 512B bank wrap)

typedef __attribute__((ext_vector_type(8))) short bf16x8;
typedef __attribute__((ext_vector_type(4))) float f32x4;

// -------- workspace layout (float offsets) --------
// X0/Y0 : bf16 @ 0        (2 x 393216 bf16)
// H     : float @ 393216  (3072*512)
// R     : float @ 1966080 (3072*256)  fp32, for src_emb output
// Rb    : bf16  @ 2752512 (3072*256 bf16) for MFMA aff/neg
// aff   : float @ 3145728 (1024)
// spPos @ 3146752, spNeg @ 3146753, rank @ 3146754 (1024 ints)

__device__ __forceinline__ float bf2f(unsigned short u) {
  return __uint_as_float(((unsigned)u) << 16);
}
__device__ __forceinline__ void store_out(float v, float* p) { *p = v; }
__device__ __forceinline__ void store_out(float v, unsigned short* p) {
  unsigned x = __float_as_uint(v);                 // f32 -> bf16 RNE
  *p = (unsigned short)((x + 0x7fff + ((x >> 16) & 1)) >> 16);
}

// Half-split matmul, 6 rows x 256 cols per 512-thread block (grid 512).
// A-tile in LDS (broadcast ds_read_b128); W coalesced from global.
// NORM: fused row L2-normalization. OutB: optional second bf16 output (Rb).
template<int K, int AW, int HOFF, bool NORM, typename OutT>
__global__ __launch_bounds__(512) void k_mm(
    const float* __restrict__ Ain,
    const float* __restrict__ W0, const float* __restrict__ W1,
    OutT* __restrict__ Out, const int ldo, const int outHalfOff,
    unsigned short* __restrict__ OutB,
    float* __restrict__ zbuf, const int zcount) {
  __shared__ float AT[6 * AW];
  __shared__ float rs[8][3];
  const int t = threadIdx.x;
  if (zbuf != nullptr && blockIdx.x == 0)
    for (int z = t; z < zcount; z += 512) zbuf[z] = 0.f;
  const int base = blockIdx.x * 6;
  {
    const float4* __restrict__ src = (const float4*)(Ain + base * AW);
    float4* __restrict__ dst = (float4*)AT;
    for (int idx = t; idx < 6 * AW / 4; idx += 512) dst[idx] = src[idx];
  }
  __syncthreads();

  const int wave = t >> 6;
  const int half = wave >> 2;
  const int colg = (wave >> 1) & 1;
  const int rowg = wave & 1;
  const int rg = rowg * 3;
  const int col = colg * 64 + (t & 63);
  const float* __restrict__ W = (half ? W1 : W0) + col;
  const float* __restrict__ A0 = AT + rg * AW + half * HOFF;

  float acc[3] = {0.f, 0.f, 0.f};
#pragma unroll 4
  for (int d = 0; d < K; d += 4) {
    float4 a[3];
#pragma unroll
    for (int r = 0; r < 3; ++r) a[r] = *(const float4*)&A0[r * AW + d];
    float w[4];
#pragma unroll
    for (int i2 = 0; i2 < 4; ++i2) w[i2] = W[(d + i2) * 128];
#pragma unroll
    for (int i2 = 0; i2 < 4; ++i2)
#pragma unroll
      for (int r = 0; r < 3; ++r)
        acc[r] = fmaf(((const float*)&a[r])[i2], w[i2], acc[r]);
  }

  float scale[3] = {1.f, 1.f, 1.f};
  if (NORM) {
    float p[3];
#pragma unroll
    for (int r = 0; r < 3; ++r) p[r] = acc[r] * acc[r];
#pragma unroll
    for (int off = 32; off > 0; off >>= 1)
#pragma unroll
      for (int r = 0; r < 3; ++r) p[r] += __shfl_xor(p[r], off, 64);
    if ((t & 63) == 0) { rs[wave][0] = p[0]; rs[wave][1] = p[1]; rs[wave][2] = p[2]; }
    __syncthreads();
#pragma unroll
    for (int r = 0; r < 3; ++r) {
      const float s = rs[rowg][r] + rs[rowg + 2][r] + rs[rowg + 4][r] + rs[rowg + 6][r];
      scale[r] = rsqrtf(fmaxf(s, 1e-12f));
    }
  }
  OutT* __restrict__ O = Out + half * outHalfOff;
#pragma unroll
  for (int r = 0; r < 3; ++r) {
    const float v = acc[r] * scale[r];
    store_out(v, &O[(base + rg + r) * ldo + col]);
    if (OutB != nullptr)
      store_out(v, &OutB[(base + rg + r) * 256 + half * 128 + col]);
  }
}

// Fused layer-0 + layer-1 aggregation, bf16 gathers, ONE barrier.
// (unchanged from R6/R8 — see journal)
__global__ __launch_bounds__(640) void k_aggregate(
    const unsigned short* __restrict__ X0, const unsigned short* __restrict__ Y0,
    const int* __restrict__ nb0, const int* __restrict__ nb1,
    const int* __restrict__ nb2, float* __restrict__ H) {
  __shared__ float gB[10][128], gC[10][128], gD[10][128];
  const int i = blockIdx.x;
  const int t = threadIdx.x;
  const int n0 = nb0[i];
  const int j = t >> 6;
  const int lam = t & 63;
  const int r = i * 10 + j;
  int myidx = 0;
  if (lam < 25) myidx = nb2[r * 25 + lam];
  else if (lam == 25) myidx = nb1[r];
  const int c8 = lam & 15;
  const int sub = lam >> 4;

  float d8[8];
#pragma unroll
  for (int e = 0; e < 8; ++e) d8[e] = 0.f;
#pragma unroll
  for (int m = 0; m < 7; ++m) {
    const int k = sub + 4 * m;
    const int ridx = __shfl(myidx, k, 64);
    if (k < 25) {
      const float4 raw = *(const float4*)(Y0 + ridx * 128 + c8 * 8);
      const unsigned short* u = (const unsigned short*)&raw;
#pragma unroll
      for (int e = 0; e < 8; ++e) d8[e] += bf2f(u[e]);
    }
  }
#pragma unroll
  for (int e = 0; e < 8; ++e) d8[e] += __shfl_xor(d8[e], 16, 64);
#pragma unroll
  for (int e = 0; e < 8; ++e) d8[e] += __shfl_xor(d8[e], 32, 64);

  const int r1 = __shfl(myidx, 25, 64);
  if (sub == 0) {
#pragma unroll
    for (int e = 0; e < 8; ++e) gD[j][c8 * 8 + e] = fmaxf(d8[e] * 0.04f, 0.f);
    const float4 raw = *(const float4*)(Y0 + r1 * 128 + c8 * 8);
    const unsigned short* u = (const unsigned short*)&raw;
#pragma unroll
    for (int e = 0; e < 8; ++e) gB[j][c8 * 8 + e] = bf2f(u[e]);
  } else if (sub == 1) {
    const float4 raw = *(const float4*)(X0 + r1 * 128 + c8 * 8);
    const unsigned short* u = (const unsigned short*)&raw;
#pragma unroll
    for (int e = 0; e < 8; ++e) gC[j][c8 * 8 + e] = fmaxf(bf2f(u[e]), 0.f);
  }
  __syncthreads();

  if (t < 512) {
    const int q = t >> 7, c = t & 127;
    float v;
    if (q == 0) {
      v = fmaxf(bf2f(X0[n0 * 128 + c]), 0.f);
    } else {
      const float* g = (q == 1) ? &gB[0][0] : (q == 2) ? &gC[0][0] : &gD[0][0];
      float s = 0.f;
#pragma unroll
      for (int jj = 0; jj < 10; ++jj) s += g[jj * 128 + c];
      v = s * 0.1f;
      if (q == 1) v = fmaxf(v, 0.f);
    }
    H[i * 512 + t] = v;
  }
}

__device__ __forceinline__ float softplusf(float x) {
  return fmaxf(x, 0.f) + log1pf(expf(-fabsf(x)));
}

// aff via MFMA: one wave per 16 rows; aff[r] = diag(S @ P^T)[r] using the
// BIT-IDENTICAL mfma sequence (same shape, k0 ascending, zero-init) as
// k_neg — a tied neg column (same node as pos) has identical fragments ->
// identical fp32 MFMA output -> exact-tie reproduction for the reference's
// stable double-argsort. Also writes src_emb (fp32 R) and spPos.
__global__ __launch_bounds__(64) void k_aff(
    const unsigned short* __restrict__ Rb, const float* __restrict__ R,
    const int* __restrict__ src_idx, const int* __restrict__ pos_idx,
    float* __restrict__ out_src, float* __restrict__ aff,
    float* __restrict__ spPos) {
  __shared__ unsigned short Sb[16][LDP];
  __shared__ unsigned short Pb[16][LDP];
  const int t = threadIdx.x;
  const int rowBase = blockIdx.x * 16;
  for (int idx = t; idx < 32 * 32; idx += 64) {
    const int row = idx >> 5, q = idx & 31;
    const int gr = (row < 16) ? src_idx[rowBase + row] : pos_idx[rowBase + row - 16];
    const float4 v = ((const float4*)(Rb + gr * 256))[q];
    unsigned short* dst = (row < 16) ? &Sb[row][0] : &Pb[row - 16][0];
    *(float4*)(dst + q * 8) = v;
  }
  for (int idx = t; idx < 16 * 64; idx += 64) {
    const int row = idx >> 6, q = idx & 63;
    ((float4*)out_src)[(rowBase + row) * 64 + q] =
        ((const float4*)(R + src_idx[rowBase + row] * 256))[q];
  }
  __syncthreads();
  const int lm = t & 15, quad = t >> 4;
  const unsigned short* Sp = &Sb[lm][quad * 8];
  const unsigned short* Pp = &Pb[lm][quad * 8];
  f32x4 d = {0.f, 0.f, 0.f, 0.f};
#pragma unroll
  for (int k0 = 0; k0 < 256; k0 += 32) {
    bf16x8 a = *(const bf16x8*)(Sp + k0);
    bf16x8 b = *(const bf16x8*)(Pp + k0);
    d = __builtin_amdgcn_mfma_f32_16x16x32_bf16(a, b, d, 0, 0, 0);
  }
  // C/D layout: col = lane&15, row = quad*4+reg -> diagonal where col==row
#pragma unroll
  for (int j = 0; j < 4; ++j) {
    const int row = quad * 4 + j;
    if (lm == row) {
      aff[rowBase + row] = d[j];
      atomicAdd(spPos, softplusf(-d[j]));
    }
  }
}

// neg_aff via MFMA: 32 src rows x 64 neg cols per 256-thread block
// (grid 256, LDS 50.7 KB -> 3 blocks/CU). Stage 96 bf16 rows; per wave:
// 8 K-steps x (3 ds_read_b128 frags + 2 mfma_16x16x32_bf16). Epilogue:
// softplus into spNeg; rank += count(neg_aff >= aff) (ties exact via k_aff's
// identical MFMA sequence; positive sorts last in the stable argsort).
__global__ __launch_bounds__(256) void k_neg(
    const unsigned short* __restrict__ Rb, const int* __restrict__ src_idx,
    const int* __restrict__ neg_idx, const float* __restrict__ aff,
    int* __restrict__ rank, float* __restrict__ spNeg) {
  __shared__ unsigned short Sb[32][LDP];
  __shared__ unsigned short Nb[64][LDP];
  __shared__ float affL[32];
  const int t = threadIdx.x;
  const int rowBase = (blockIdx.x >> 3) * 32;
  const int colBase = (blockIdx.x & 7) * 64;
  if (t < 32) affL[t] = aff[rowBase + t];
  for (int idx = t; idx < 96 * 32; idx += 256) {
    const int row = idx >> 5, q = idx & 31;
    const int gr = (row < 32) ? src_idx[rowBase + row]
                              : neg_idx[colBase + row - 32];
    const float4 v = ((const float4*)(Rb + gr * 256))[q];
    unsigned short* dst = (row < 32) ? &Sb[row][0] : &Nb[row - 32][0];
    *(float4*)(dst + q * 8) = v;
  }
  __syncthreads();

  const int l = t & 63, w = t >> 6;
  const int mt = w & 1, np = w >> 1;
  const int lm = l & 15, quad = l >> 4;
  const unsigned short* Sp = &Sb[mt * 16 + lm][quad * 8];
  const unsigned short* N0 = &Nb[np * 32 + lm][quad * 8];
  const unsigned short* N1 = &Nb[np * 32 + 16 + lm][quad * 8];
  f32x4 d0 = {0.f, 0.f, 0.f, 0.f}, d1 = {0.f, 0.f, 0.f, 0.f};
#pragma unroll
  for (int k0 = 0; k0 < 256; k0 += 32) {
    bf16x8 a = *(const bf16x8*)(Sp + k0);
    bf16x8 b0 = *(const bf16x8*)(N0 + k0);
    bf16x8 b1 = *(const bf16x8*)(N1 + k0);
    d0 = __builtin_amdgcn_mfma_f32_16x16x32_bf16(a, b0, d0, 0, 0, 0);
    d1 = __builtin_amdgcn_mfma_f32_16x16x32_bf16(a, b1, d1, 0, 0, 0);
  }

  float sp = 0.f;
#pragma unroll
  for (int j = 0; j < 4; ++j) {
    const int row = mt * 16 + quad * 4 + j;
    const float a = affL[row];
    const float v0 = d0[j], v1 = d1[j];
    sp += softplusf(v0) + softplusf(v1);
    int c = (v0 >= a ? 1 : 0) + (v1 >= a ? 1 : 0);
#pragma unroll
    for (int off = 8; off > 0; off >>= 1) c += __shfl_down(c, off, 16);
    if (lm == 0 && c) atomicAdd(&rank[rowBase + row], c);
  }
#pragma unroll
  for (int off = 32; off > 0; off >>= 1) sp += __shfl_down(sp, off, 64);
  if (l == 0) atomicAdd(spNeg, sp);
}

// mrr + loss scalars.
__global__ __launch_bounds__(256) void k_finalize(
    const int* __restrict__ rank, const float* __restrict__ spPos,
    const float* __restrict__ spNeg, float* __restrict__ out) {
  const int t = threadIdx.x;
  float s = 0.f;
  for (int i = t; i < BATCH; i += 256) s += 1.f / (float)(rank[i] + 1);
#pragma unroll
  for (int off = 32; off > 0; off >>= 1) s += __shfl_down(s, off, 64);
  __shared__ float wsum[4];
  if ((t & 63) == 0) wsum[t >> 6] = s;
  __syncthreads();
  if (t == 0) {
    float mrr = (wsum[0] + wsum[1] + wsum[2] + wsum[3]) * (1.f / 1024.f);
    float loss = (spPos[0] + spNeg[0]) * (1.f / 1024.f);
    out[BATCH * 256]     = loss;
    out[BATCH * 256 + 1] = mrr;
  }
}

extern "C" void kernel_launch(void* const* d_in, const int* in_sizes, int n_in,
                              void* d_out, int out_size, void* d_ws, size_t ws_size,
                              hipStream_t stream) {
  const float* feat   = (const float*)d_in[1];
  const int* src_idx  = (const int*)d_in[2];
  const int* pos_idx  = (const int*)d_in[3];
  const int* neg_idx  = (const int*)d_in[4];
  const int* nb0      = (const int*)d_in[5];
  const int* nb1      = (const int*)d_in[6];
  const int* nb2      = (const int*)d_in[7];
  const float* ws0    = (const float*)d_in[8];
  const float* wn0    = (const float*)d_in[9];
  const float* ws1    = (const float*)d_in[10];
  const float* wn1    = (const float*)d_in[11];

  float* wsf = (float*)d_ws;
  unsigned short* X0 = (unsigned short*)d_ws;        // bf16[393216]
  unsigned short* Y0 = X0 + 393216;                  // bf16[393216]
  float* H     = wsf + 393216;                       // 3072*512
  float* R     = wsf + 1966080;                      // 3072*256 fp32
  unsigned short* Rb = (unsigned short*)(wsf + 2752512);  // 3072*256 bf16
  float* aff   = wsf + 3145728;
  float* spPos = wsf + 3146752;
  float* spNeg = wsf + 3146753;
  int*   rank  = (int*)(wsf + 3146754);
  float* out   = (float*)d_out;

  // X0 = bf16(feat@ws0), Y0 = bf16(feat@wn0); block 0 zeroes spPos/spNeg/rank
  k_mm<128, 128, 0, false, unsigned short><<<L0 / 6, 512, 0, stream>>>(
      feat, ws0, wn0, X0, 128, 393216, nullptr, spPos, 1026);
  k_aggregate<<<L0, 640, 0, stream>>>(X0, Y0, nb0, nb1, nb2, H);
  // R = normalized layer-1 output (fp32) + Rb (bf16 copy for MFMA)
  k_mm<256, 512, 256, true, float><<<L0 / 6, 512, 0, stream>>>(
      H, ws1, wn1, R, 256, 128, Rb, nullptr, 0);
  k_aff<<<BATCH / 16, 64, 0, stream>>>(Rb, R, src_idx, pos_idx, out, aff, spPos);
  k_neg<<<(BATCH / 32) * (NNEG / 64), 256, 0, stream>>>(
      Rb, src_idx, neg_idx, aff, rank, spNeg);
  k_finalize<<<1, 256, 0, stream>>>(rank, spPos, spNeg, out);
}